// Round 13
// baseline (1073.197 us; speedup 1.0000x reference)
//
#include <hip/hip_runtime.h>

#define NROWS 65536
#define FEA   512
#define MEM   2000
#define MEMP  2048
#define LAMBDA 0.0025f
#define EPS    1e-12f

#define PLX ((long)NROWS * FEA)   // elements per x plane
#define PLW ((long)MEMP * FEA)    // elements per W plane

typedef unsigned short ushort_t;
typedef __attribute__((ext_vector_type(8))) short bf16x8;
typedef __attribute__((ext_vector_type(4))) float f32x4;

// ---------- bf16 split helpers (RNE) ----------
__device__ inline ushort_t f2bf(float f) {
  unsigned int u = __float_as_uint(f);
  unsigned int r = (u + 0x7FFFu + ((u >> 16) & 1u)) >> 16;
  return (ushort_t)r;
}
__device__ inline float bf2f(ushort_t h) {
  return __uint_as_float(((unsigned int)h) << 16);
}

__device__ inline void gload_lds16(const void* g, void* l) {
  __builtin_amdgcn_global_load_lds(
      (const __attribute__((address_space(1))) unsigned int*)g,
      (__attribute__((address_space(3))) unsigned int*)l, 16, 0, 0);
}

// ------------------------------------------------------------------
// K0: split x AND W -> hi/lo bf16 planes in ONE launch.
// blocks [0,2048): x grid-stride; blocks [2048,3072): W (padded 2048).
// ------------------------------------------------------------------
__global__ __launch_bounds__(256) void split_all(const float* __restrict__ x,
                                                 const float* __restrict__ W,
                                                 ushort_t* __restrict__ xpl,
                                                 ushort_t* __restrict__ wpl) {
  if (blockIdx.x < 2048) {
    const long n4 = PLX / 4;
    long i = (long)blockIdx.x * 256 + threadIdx.x;
    const long stride = 2048L * 256;
    for (; i < n4; i += stride) {
      float4 v = ((const float4*)x)[i];
      float f[4] = {v.x, v.y, v.z, v.w};
      ushort_t hh[4], ll[4];
#pragma unroll
      for (int j = 0; j < 4; ++j) {
        hh[j] = f2bf(f[j]);
        ll[j] = f2bf(f[j] - bf2f(hh[j]));
      }
      ushort4 h; h.x = hh[0]; h.y = hh[1]; h.z = hh[2]; h.w = hh[3];
      ushort4 l; l.x = ll[0]; l.y = ll[1]; l.z = ll[2]; l.w = ll[3];
      ((ushort4*)xpl)[i] = h;
      ((ushort4*)(xpl + PLX))[i] = l;
    }
  } else {
    long i = (long)(blockIdx.x - 2048) * 256 + threadIdx.x;
    if (i >= PLW / 4) return;
    long row = i / (FEA / 4);
    ushort4 h = {0, 0, 0, 0}, l = {0, 0, 0, 0};
    if (row < MEM) {
      float4 v = ((const float4*)W)[i];
      float f[4] = {v.x, v.y, v.z, v.w};
      ushort_t hh[4], ll[4];
#pragma unroll
      for (int j = 0; j < 4; ++j) {
        hh[j] = f2bf(f[j]);
        ll[j] = f2bf(f[j] - bf2f(hh[j]));
      }
      h.x = hh[0]; h.y = hh[1]; h.z = hh[2]; h.w = hh[3];
      l.x = ll[0]; l.y = ll[1]; l.z = ll[2]; l.w = ll[3];
    }
    ((ushort4*)wpl)[i] = h;
    ((ushort4*)(wpl + PLW))[i] = l;
  }
}

// ------------------------------------------------------------------
// K1: S = x @ W^T, split-bf16 (3 products), 256x256 tile, BK=32,
// 16x16x32 MFMA, conflict-free lane map, ring-2, one vmcnt(0)+barrier
// per K-tile — but now 1024 THREADS = 16 waves (4M x 4N) = 4 waves/
// SIMD: TLP-driven overlap of ds_read and MFMA across drifting waves.
// Wave tile 64x64: acc 4x4xf32x4 = 64 VGPR. __launch_bounds__(1024,4)
// caps VGPR at 128 so the 16-wave block fits one CU.
// Slot: [256 rows][128 B] = 2 planes x 4 k-octets; phys = c^(row&7).
// ------------------------------------------------------------------
__global__ __launch_bounds__(1024, 4) void gemm_mfma11(
    const ushort_t* __restrict__ xpl, const ushort_t* __restrict__ wpl,
    float* __restrict__ S) {
  __shared__ alignas(16) ushort_t lds[65536];  // A 2-slot 64 KB | B 2-slot 64 KB

  const int tid = threadIdx.x;
  const int wid = tid >> 6, lane = tid & 63;
  const int l15 = lane & 15, lq = lane >> 4, rx = l15 & 7;
  const int wm = wid >> 2, wn = wid & 3;       // 4M x 4N waves

  // XCD-chunked bijective swizzle (2048 wgs): proven 197 MB fetch
  int wg = blockIdx.x;
  int xcd = wg & 7, idx = wg >> 3;
  const int mt = xcd * 32 + (idx >> 3);
  const int nt = idx & 7;
  const long rm0 = (long)mt * 256;
  const long cn0 = (long)nt * 256;

  // per-lane LDS read bases (ushort units)
  const int aB0 = (wm * 64 + l15) * 64 + ((lq ^ rx) * 8);
  const int bB0 = 32768 + (wn * 64 + l15) * 64 + ((lq ^ rx) * 8);

  // per-thread stage offsets (1024 threads, 2 units each per operand)
  int sDst[2], sOffX[2], sOffW[2];
#pragma unroll
  for (int i = 0; i < 2; ++i) {
    int id = i * 1024 + tid;         // 16B-position 0..2047
    int row = id >> 3;
    int ls = (id & 7) ^ (row & 7);
    sDst[i] = id * 8;
    sOffX[i] = (ls >> 2) * (int)PLX + row * FEA + (ls & 3) * 8;
    sOffW[i] = (ls >> 2) * (int)PLW + row * FEA + (ls & 3) * 8;
  }
  const ushort_t* xb = xpl + rm0 * FEA;
  const ushort_t* wb = wpl + cn0 * FEA;

  f32x4 acc[4][4] = {};

  auto stage = [&](int t, int sl) {
    const ushort_t* xs = xb + t * 32;
    const ushort_t* ws = wb + t * 32;
    ushort_t* dA = (ushort_t*)lds + sl * 16384;
    ushort_t* dB = (ushort_t*)lds + 32768 + sl * 16384;
#pragma unroll
    for (int i = 0; i < 2; ++i) gload_lds16(xs + sOffX[i], dA + sDst[i]);
#pragma unroll
    for (int i = 0; i < 2; ++i) gload_lds16(ws + sOffW[i], dB + sDst[i]);
  };

  auto tile = [&](int t, int SLOT, bool last) {
    const ushort_t* L = (const ushort_t*)lds;
    const int so = SLOT * 16384;

    bf16x8 b[4][2];
#pragma unroll
    for (int nf = 0; nf < 4; ++nf) {
      b[nf][0] = *(const bf16x8*)(L + ((bB0 + so + nf * 1024)));
      b[nf][1] = *(const bf16x8*)(L + ((bB0 + so + nf * 1024) ^ 32));
    }
    if (!last) stage(t + 1, SLOT ^ 1);

#pragma unroll
    for (int mi = 0; mi < 4; ++mi) {
      bf16x8 a0 = *(const bf16x8*)(L + ((aB0 + so + mi * 1024)));
      bf16x8 a1 = *(const bf16x8*)(L + ((aB0 + so + mi * 1024) ^ 32));
#pragma unroll
      for (int nf = 0; nf < 4; ++nf)
        acc[mi][nf] = __builtin_amdgcn_mfma_f32_16x16x32_bf16(
            a0, b[nf][0], acc[mi][nf], 0, 0, 0);
#pragma unroll
      for (int nf = 0; nf < 4; ++nf)
        acc[mi][nf] = __builtin_amdgcn_mfma_f32_16x16x32_bf16(
            a0, b[nf][1], acc[mi][nf], 0, 0, 0);
#pragma unroll
      for (int nf = 0; nf < 4; ++nf)
        acc[mi][nf] = __builtin_amdgcn_mfma_f32_16x16x32_bf16(
            a1, b[nf][0], acc[mi][nf], 0, 0, 0);
    }

    if (!last) {
      asm volatile("s_waitcnt vmcnt(0)" ::: "memory");
      asm volatile("s_barrier" ::: "memory");
    }
  };

  // prologue
  stage(0, 0);
  asm volatile("s_waitcnt vmcnt(0)" ::: "memory");
  asm volatile("s_barrier" ::: "memory");

  for (int tt = 0; tt < 7; ++tt) {
    tile(2 * tt, 0, false);
    tile(2 * tt + 1, 1, false);
  }
  tile(14, 0, false);
  tile(15, 1, true);

  // epilogue: 16x16 C/D layout col = lane&15, row = (lane>>4)*4 + reg
#pragma unroll
  for (int mf = 0; mf < 4; ++mf)
#pragma unroll
    for (int nf = 0; nf < 4; ++nf) {
      int col = (int)cn0 + wn * 64 + nf * 16 + l15;
      if (col < MEM) {
        long rbase = rm0 + wm * 64 + mf * 16 + lq * 4;
#pragma unroll
        for (int r = 0; r < 4; ++r)
          S[(rbase + r) * MEM + col] = acc[mf][nf][r];
      }
    }
}

// ------------------------------------------------------------------
// Fallback fp32 GEMM (used only if ws too small)
// ------------------------------------------------------------------
#define BKF 32
__global__ __launch_bounds__(256) void gemm_scores(
    const float* __restrict__ x, const float* __restrict__ Wt,
    float* __restrict__ S) {
  __shared__ float xs[BKF][129];
  __shared__ float ws[BKF][129];
  const int tid = threadIdx.x;
  const int rm0 = blockIdx.x * 128;
  const int cn0 = blockIdx.y * 128;
  const int tx = tid & 15, ty = tid >> 4;
  const int sr = tid >> 3, kq = tid & 7;
  float acc[8][8];
#pragma unroll
  for (int i = 0; i < 8; ++i)
#pragma unroll
    for (int j = 0; j < 8; ++j) acc[i][j] = 0.f;
  for (int k0 = 0; k0 < FEA; k0 += BKF) {
#pragma unroll
    for (int b = 0; b < 4; ++b) {
      const int row = sr + 32 * b;
      float4 v = *(const float4*)(x + (size_t)(rm0 + row) * FEA + k0 + kq * 4);
      xs[kq * 4 + 0][row] = v.x; xs[kq * 4 + 1][row] = v.y;
      xs[kq * 4 + 2][row] = v.z; xs[kq * 4 + 3][row] = v.w;
      int wr = cn0 + row; wr = (wr < MEM) ? wr : (MEM - 1);
      float4 u = *(const float4*)(Wt + (size_t)wr * FEA + k0 + kq * 4);
      ws[kq * 4 + 0][row] = u.x; ws[kq * 4 + 1][row] = u.y;
      ws[kq * 4 + 2][row] = u.z; ws[kq * 4 + 3][row] = u.w;
    }
    __syncthreads();
#pragma unroll 8
    for (int k = 0; k < BKF; ++k) {
      float a[8], bb[8];
      float4 t0 = *(const float4*)&xs[k][4 * ty];
      float4 t1 = *(const float4*)&xs[k][64 + 4 * ty];
      a[0] = t0.x; a[1] = t0.y; a[2] = t0.z; a[3] = t0.w;
      a[4] = t1.x; a[5] = t1.y; a[6] = t1.z; a[7] = t1.w;
      float4 u0 = *(const float4*)&ws[k][4 * tx];
      float4 u1 = *(const float4*)&ws[k][64 + 4 * tx];
      bb[0] = u0.x; bb[1] = u0.y; bb[2] = u0.z; bb[3] = u0.w;
      bb[4] = u1.x; bb[5] = u1.y; bb[6] = u1.z; bb[7] = u1.w;
#pragma unroll
      for (int i = 0; i < 8; ++i)
#pragma unroll
        for (int j = 0; j < 8; ++j)
          acc[i][j] = fmaf(a[i], bb[j], acc[i][j]);
    }
    __syncthreads();
  }
#pragma unroll
  for (int i = 0; i < 8; ++i) {
    const int row = rm0 + ((i < 4) ? (4 * ty + i) : (64 + 4 * ty + (i - 4)));
    const int c0 = cn0 + 4 * tx;
    const int c1 = cn0 + 64 + 4 * tx;
    if (c0 < MEM) {
      float4 v; v.x = acc[i][0]; v.y = acc[i][1]; v.z = acc[i][2]; v.w = acc[i][3];
      *(float4*)(S + (size_t)row * MEM + c0) = v;
    }
    if (c1 < MEM) {
      float4 v; v.x = acc[i][4]; v.y = acc[i][5]; v.z = acc[i][6]; v.w = acc[i][7];
      *(float4*)(S + (size_t)row * MEM + c1) = v;
    }
  }
}

// ------------------------------------------------------------------
// K2: softmax -> hard shrink -> renorm -> write att + sparse out
// ------------------------------------------------------------------
__global__ __launch_bounds__(512) void softmax_shrink_out(
    const float* __restrict__ Wt, float* __restrict__ out,
    float* __restrict__ att /* raw scores on entry */) {
  __shared__ float sl[8 * MEM];
  const int tid = threadIdx.x;
  const int r0 = blockIdx.x * 8;
  {
    const float* Sblk = att + (size_t)r0 * MEM;
#pragma unroll
    for (int jj = 0; jj < 8; ++jj) {
      int q = tid + 512 * jj;
      if (q < (8 * MEM) / 4) {
        float4 v = *(const float4*)(Sblk + 4 * q);
        *(float4*)&sl[4 * q] = v;
      }
    }
  }
  __syncthreads();
  const int w = tid >> 6;
  const int l = tid & 63;
  float* row_lds = &sl[w * MEM];
  const int grow = r0 + w;

  float m = -INFINITY;
  for (int j = 0; j < 32; ++j) {
    int c = l + 64 * j;
    if (c < MEM) m = fmaxf(m, row_lds[c]);
  }
#pragma unroll
  for (int off = 32; off; off >>= 1) m = fmaxf(m, __shfl_xor(m, off));

  float s = 0.f;
  for (int j = 0; j < 32; ++j) {
    int c = l + 64 * j;
    if (c < MEM) {
      float e = expf(row_lds[c] - m);
      row_lds[c] = e;
      s += e;
    }
  }
#pragma unroll
  for (int off = 32; off; off >>= 1) s += __shfl_xor(s, off);

  float qs = 0.f;
  for (int j = 0; j < 32; ++j) {
    int c = l + 64 * j;
    if (c < MEM) {
      float p = row_lds[c] / s;
      float d = p - LAMBDA;
      float q = fmaxf(d, 0.f) * p / (fabsf(d) + EPS);
      row_lds[c] = q;
      qs += q;
    }
  }
#pragma unroll
  for (int off = 32; off; off >>= 1) qs += __shfl_xor(qs, off);
  const float denom = fmaxf(qs, EPS);

  float4 oa0 = {0.f, 0.f, 0.f, 0.f};
  float4 oa1 = {0.f, 0.f, 0.f, 0.f};
  for (int j = 0; j < 32; ++j) {
    int c = l + 64 * j;
    float a = 0.f;
    if (c < MEM) {
      a = row_lds[c] / denom;
      att[(size_t)grow * MEM + c] = a;
    }
    unsigned long long msk = __ballot(a > 0.f);
    while (msk) {
      int b = __ffsll(msk) - 1;
      msk &= msk - 1;
      float av = __shfl(a, b);
      int cc = b + 64 * j;
      const float* wp = Wt + (size_t)cc * FEA;
      float4 w0 = *(const float4*)(wp + 4 * l);
      float4 w1 = *(const float4*)(wp + 256 + 4 * l);
      oa0.x = fmaf(av, w0.x, oa0.x); oa0.y = fmaf(av, w0.y, oa0.y);
      oa0.z = fmaf(av, w0.z, oa0.z); oa0.w = fmaf(av, w0.w, oa0.w);
      oa1.x = fmaf(av, w1.x, oa1.x); oa1.y = fmaf(av, w1.y, oa1.y);
      oa1.z = fmaf(av, w1.z, oa1.z); oa1.w = fmaf(av, w1.w, oa1.w);
    }
  }
  float* op = out + (size_t)grow * FEA;
  *(float4*)(op + 4 * l) = oa0;
  *(float4*)(op + 256 + 4 * l) = oa1;
}

// ------------------------------------------------------------------
extern "C" void kernel_launch(void* const* d_in, const int* in_sizes, int n_in,
                              void* d_out, int out_size, void* d_ws, size_t ws_size,
                              hipStream_t stream) {
  (void)in_sizes; (void)n_in; (void)out_size;
  const float* x = (const float*)d_in[0];
  const float* W = (const float*)d_in[1];
  float* out = (float*)d_out;
  float* att = (float*)d_out + (size_t)NROWS * FEA;

  const size_t w_need = (size_t)PLW * 2 * sizeof(ushort_t);  // 4 MB
  if (ws_size >= w_need) {
    ushort_t* xpl = (ushort_t*)d_out;  // out region: exactly fits 2 x-planes
    ushort_t* wpl = (ushort_t*)d_ws;
    split_all<<<3072, 256, 0, stream>>>(x, W, xpl, wpl);
    gemm_mfma11<<<2048, 1024, 0, stream>>>(xpl, wpl, att);
  } else {
    dim3 g1(NROWS / 128, (MEM + 127) / 128);
    gemm_scores<<<g1, 256, 0, stream>>>(x, W, att);
  }
  softmax_shrink_out<<<NROWS / 8, 512, 0, stream>>>(W, out, att);
}

// Round 14
// 973.048 us; speedup vs baseline: 1.1029x; 1.1029x over previous
//
#include <hip/hip_runtime.h>

#define NROWS 65536
#define FEA   512
#define MEM   2000
#define MEMP  2048
#define LAMBDA 0.0025f
#define EPS    1e-12f

#define PLX ((long)NROWS * FEA)   // elements per x plane
#define PLW ((long)MEMP * FEA)    // elements per W plane

typedef unsigned short ushort_t;
typedef __attribute__((ext_vector_type(8))) short bf16x8;
typedef __attribute__((ext_vector_type(4))) float f32x4;

// ---------- bf16 split helpers (RNE) ----------
__device__ inline ushort_t f2bf(float f) {
  unsigned int u = __float_as_uint(f);
  unsigned int r = (u + 0x7FFFu + ((u >> 16) & 1u)) >> 16;
  return (ushort_t)r;
}
__device__ inline float bf2f(ushort_t h) {
  return __uint_as_float(((unsigned int)h) << 16);
}

__device__ inline void gload_lds16(const void* g, void* l) {
  __builtin_amdgcn_global_load_lds(
      (const __attribute__((address_space(1))) unsigned int*)g,
      (__attribute__((address_space(3))) unsigned int*)l, 16, 0, 0);
}

// ------------------------------------------------------------------
// K0: split x AND W -> hi/lo bf16 planes in ONE launch.
// ------------------------------------------------------------------
__global__ __launch_bounds__(256) void split_all(const float* __restrict__ x,
                                                 const float* __restrict__ W,
                                                 ushort_t* __restrict__ xpl,
                                                 ushort_t* __restrict__ wpl) {
  if (blockIdx.x < 2048) {
    const long n4 = PLX / 4;
    long i = (long)blockIdx.x * 256 + threadIdx.x;
    const long stride = 2048L * 256;
    for (; i < n4; i += stride) {
      float4 v = ((const float4*)x)[i];
      float f[4] = {v.x, v.y, v.z, v.w};
      ushort_t hh[4], ll[4];
#pragma unroll
      for (int j = 0; j < 4; ++j) {
        hh[j] = f2bf(f[j]);
        ll[j] = f2bf(f[j] - bf2f(hh[j]));
      }
      ushort4 h; h.x = hh[0]; h.y = hh[1]; h.z = hh[2]; h.w = hh[3];
      ushort4 l; l.x = ll[0]; l.y = ll[1]; l.z = ll[2]; l.w = ll[3];
      ((ushort4*)xpl)[i] = h;
      ((ushort4*)(xpl + PLX))[i] = l;
    }
  } else {
    long i = (long)(blockIdx.x - 2048) * 256 + threadIdx.x;
    if (i >= PLW / 4) return;
    long row = i / (FEA / 4);
    ushort4 h = {0, 0, 0, 0}, l = {0, 0, 0, 0};
    if (row < MEM) {
      float4 v = ((const float4*)W)[i];
      float f[4] = {v.x, v.y, v.z, v.w};
      ushort_t hh[4], ll[4];
#pragma unroll
      for (int j = 0; j < 4; ++j) {
        hh[j] = f2bf(f[j]);
        ll[j] = f2bf(f[j] - bf2f(hh[j]));
      }
      h.x = hh[0]; h.y = hh[1]; h.z = hh[2]; h.w = hh[3];
      l.x = ll[0]; l.y = ll[1]; l.z = ll[2]; l.w = ll[3];
    }
    ((ushort4*)wpl)[i] = h;
    ((ushort4*)(wpl + PLW))[i] = l;
  }
}

// ------------------------------------------------------------------
// K1: S = x @ W^T, split-bf16 (3 products), 128x128 tile, BK=32,
// 16x16x32 MFMA. A staged in LDS (2-slot ring, 32 KB/block, proven
// conflict-free geometry); B read DIRECTLY from L2 (W planes = 4 MB,
// cache-resident) with the same logical lane->(row,k) map. 512 thr =
// 8 waves (2M x 4N, wave 64x32, acc 32 VGPR) -> 2-3 blocks/CU of
// independent drifting streams (m114 overlap). Counted vmcnt: b(t)
// rides across the tile barrier, retired by vmcnt(2); stage A(t+1)
// retired by vmcnt(4) before barrier.
// ------------------------------------------------------------------
__global__ __launch_bounds__(512, 4) void gemm_mfma12(
    const ushort_t* __restrict__ xpl, const ushort_t* __restrict__ wpl,
    float* __restrict__ S) {
  __shared__ alignas(16) ushort_t lds[16384];  // A 2 slots x 16 KB

  const int tid = threadIdx.x;
  const int wid = tid >> 6, lane = tid & 63;
  const int l15 = lane & 15, lq = lane >> 4, rx = l15 & 7;
  const int wm = wid >> 2, wn = wid & 3;       // 2M x 4N waves

  // XCD swizzle, nt inner: 16 consecutive wgs share one A panel (L2-hot)
  int wg = blockIdx.x;                          // 8192 wgs
  int xcd = wg & 7, idx = wg >> 3;              // idx 0..1023
  const int mt = xcd * 64 + (idx >> 4);         // 0..511
  const int nt = idx & 15;
  const long rm0 = (long)mt * 128;
  const long cn0 = (long)nt * 128;

  // A LDS read base (ushort units): row = wm*64 + mi*16 + l15
  const int aB0 = (wm * 64 + l15) * 64 + ((lq ^ rx) * 8);  // plane1 = ^32

  // A stage offsets (2 units of 16 B per thread)
  int sDst[2], sOffX[2];
#pragma unroll
  for (int i = 0; i < 2; ++i) {
    int id = i * 512 + tid;          // 0..1023
    int row = id >> 3;               // 0..127
    int ls = (id & 7) ^ (row & 7);   // logical chunk (involution)
    sDst[i] = id * 8;
    sOffX[i] = (ls >> 2) * (int)PLX + row * FEA + (ls & 3) * 8;
  }
  const ushort_t* xb = xpl + rm0 * FEA;
  // B global base: row = cn0 + wn*32 + nf*16 + l15, k = t*32 + lq*8
  const ushort_t* wB = wpl + (size_t)(cn0 + wn * 32 + l15) * FEA + lq * 8;

  f32x4 acc[4][2] = {};
  bf16x8 b[2][2];

  auto stageA = [&](int t, int sl) {
    const ushort_t* xs = xb + t * 32;
    ushort_t* dA = (ushort_t*)lds + sl * 8192;
#pragma unroll
    for (int i = 0; i < 2; ++i) gload_lds16(xs + sOffX[i], dA + sDst[i]);
  };
  auto loadB = [&](int t) {
#pragma unroll
    for (int nf = 0; nf < 2; ++nf)
#pragma unroll
      for (int pl = 0; pl < 2; ++pl)
        b[nf][pl] = *(const bf16x8*)(wB + (size_t)pl * PLW + nf * 16 * FEA + t * 32);
  };

  auto tile = [&](int t, int SLOT, bool last) {
    const ushort_t* L = (const ushort_t*)lds;
    const int so = SLOT * 8192;

    if (!last) stageA(t + 1, SLOT ^ 1);
    // retire b(t): outstanding = b(t)[4 oldest] + stage[2] -> vmcnt(2)
    if (!last) asm volatile("s_waitcnt vmcnt(2)" ::: "memory");
    else       asm volatile("s_waitcnt vmcnt(0)" ::: "memory");

#pragma unroll
    for (int mi = 0; mi < 4; ++mi) {
      bf16x8 a0 = *(const bf16x8*)(L + ((aB0 + so + mi * 1024)));
      bf16x8 a1 = *(const bf16x8*)(L + ((aB0 + so + mi * 1024) ^ 32));
#pragma unroll
      for (int nf = 0; nf < 2; ++nf)
        acc[mi][nf] = __builtin_amdgcn_mfma_f32_16x16x32_bf16(
            a0, b[nf][0], acc[mi][nf], 0, 0, 0);
#pragma unroll
      for (int nf = 0; nf < 2; ++nf)
        acc[mi][nf] = __builtin_amdgcn_mfma_f32_16x16x32_bf16(
            a0, b[nf][1], acc[mi][nf], 0, 0, 0);
#pragma unroll
      for (int nf = 0; nf < 2; ++nf)
        acc[mi][nf] = __builtin_amdgcn_mfma_f32_16x16x32_bf16(
            a1, b[nf][0], acc[mi][nf], 0, 0, 0);
    }

    if (!last) {
      loadB(t + 1);  // rides across the barrier (counted, never drained)
      // retire stage A(t+1) (oldest 2), keep b(t+1) in flight
      asm volatile("s_waitcnt vmcnt(4)" ::: "memory");
      asm volatile("s_barrier" ::: "memory");
    }
  };

  // prologue: A(0) staged, b(0) in flight
  stageA(0, 0);
  loadB(0);
  asm volatile("s_waitcnt vmcnt(4)" ::: "memory");  // retire stage A(0)
  asm volatile("s_barrier" ::: "memory");

  for (int tt = 0; tt < 7; ++tt) {
    tile(2 * tt, 0, false);
    tile(2 * tt + 1, 1, false);
  }
  tile(14, 0, false);
  tile(15, 1, true);

  // epilogue: 16x16 C/D layout col = lane&15, row = (lane>>4)*4 + reg
#pragma unroll
  for (int mf = 0; mf < 4; ++mf)
#pragma unroll
    for (int nf = 0; nf < 2; ++nf) {
      int col = (int)cn0 + wn * 32 + nf * 16 + l15;
      if (col < MEM) {
        long rbase = rm0 + wm * 64 + mf * 16 + lq * 4;
#pragma unroll
        for (int r = 0; r < 4; ++r)
          S[(rbase + r) * MEM + col] = acc[mf][nf][r];
      }
    }
}

// ------------------------------------------------------------------
// Fallback fp32 GEMM (used only if ws too small)
// ------------------------------------------------------------------
#define BKF 32
__global__ __launch_bounds__(256) void gemm_scores(
    const float* __restrict__ x, const float* __restrict__ Wt,
    float* __restrict__ S) {
  __shared__ float xs[BKF][129];
  __shared__ float ws[BKF][129];
  const int tid = threadIdx.x;
  const int rm0 = blockIdx.x * 128;
  const int cn0 = blockIdx.y * 128;
  const int tx = tid & 15, ty = tid >> 4;
  const int sr = tid >> 3, kq = tid & 7;
  float acc[8][8];
#pragma unroll
  for (int i = 0; i < 8; ++i)
#pragma unroll
    for (int j = 0; j < 8; ++j) acc[i][j] = 0.f;
  for (int k0 = 0; k0 < FEA; k0 += BKF) {
#pragma unroll
    for (int b = 0; b < 4; ++b) {
      const int row = sr + 32 * b;
      float4 v = *(const float4*)(x + (size_t)(rm0 + row) * FEA + k0 + kq * 4);
      xs[kq * 4 + 0][row] = v.x; xs[kq * 4 + 1][row] = v.y;
      xs[kq * 4 + 2][row] = v.z; xs[kq * 4 + 3][row] = v.w;
      int wr = cn0 + row; wr = (wr < MEM) ? wr : (MEM - 1);
      float4 u = *(const float4*)(Wt + (size_t)wr * FEA + k0 + kq * 4);
      ws[kq * 4 + 0][row] = u.x; ws[kq * 4 + 1][row] = u.y;
      ws[kq * 4 + 2][row] = u.z; ws[kq * 4 + 3][row] = u.w;
    }
    __syncthreads();
#pragma unroll 8
    for (int k = 0; k < BKF; ++k) {
      float a[8], bb[8];
      float4 t0 = *(const float4*)&xs[k][4 * ty];
      float4 t1 = *(const float4*)&xs[k][64 + 4 * ty];
      a[0] = t0.x; a[1] = t0.y; a[2] = t0.z; a[3] = t0.w;
      a[4] = t1.x; a[5] = t1.y; a[6] = t1.z; a[7] = t1.w;
      float4 u0 = *(const float4*)&ws[k][4 * tx];
      float4 u1 = *(const float4*)&ws[k][64 + 4 * tx];
      bb[0] = u0.x; bb[1] = u0.y; bb[2] = u0.z; bb[3] = u0.w;
      bb[4] = u1.x; bb[5] = u1.y; bb[6] = u1.z; bb[7] = u1.w;
#pragma unroll
      for (int i = 0; i < 8; ++i)
#pragma unroll
        for (int j = 0; j < 8; ++j)
          acc[i][j] = fmaf(a[i], bb[j], acc[i][j]);
    }
    __syncthreads();
  }
#pragma unroll
  for (int i = 0; i < 8; ++i) {
    const int row = rm0 + ((i < 4) ? (4 * ty + i) : (64 + 4 * ty + (i - 4)));
    const int c0 = cn0 + 4 * tx;
    const int c1 = cn0 + 64 + 4 * tx;
    if (c0 < MEM) {
      float4 v; v.x = acc[i][0]; v.y = acc[i][1]; v.z = acc[i][2]; v.w = acc[i][3];
      *(float4*)(S + (size_t)row * MEM + c0) = v;
    }
    if (c1 < MEM) {
      float4 v; v.x = acc[i][4]; v.y = acc[i][5]; v.z = acc[i][6]; v.w = acc[i][7];
      *(float4*)(S + (size_t)row * MEM + c1) = v;
    }
  }
}

// ------------------------------------------------------------------
// K2: softmax -> hard shrink -> renorm -> write att + sparse out
// ------------------------------------------------------------------
__global__ __launch_bounds__(512) void softmax_shrink_out(
    const float* __restrict__ Wt, float* __restrict__ out,
    float* __restrict__ att /* raw scores on entry */) {
  __shared__ float sl[8 * MEM];
  const int tid = threadIdx.x;
  const int r0 = blockIdx.x * 8;
  {
    const float* Sblk = att + (size_t)r0 * MEM;
#pragma unroll
    for (int jj = 0; jj < 8; ++jj) {
      int q = tid + 512 * jj;
      if (q < (8 * MEM) / 4) {
        float4 v = *(const float4*)(Sblk + 4 * q);
        *(float4*)&sl[4 * q] = v;
      }
    }
  }
  __syncthreads();
  const int w = tid >> 6;
  const int l = tid & 63;
  float* row_lds = &sl[w * MEM];
  const int grow = r0 + w;

  float m = -INFINITY;
  for (int j = 0; j < 32; ++j) {
    int c = l + 64 * j;
    if (c < MEM) m = fmaxf(m, row_lds[c]);
  }
#pragma unroll
  for (int off = 32; off; off >>= 1) m = fmaxf(m, __shfl_xor(m, off));

  float s = 0.f;
  for (int j = 0; j < 32; ++j) {
    int c = l + 64 * j;
    if (c < MEM) {
      float e = expf(row_lds[c] - m);
      row_lds[c] = e;
      s += e;
    }
  }
#pragma unroll
  for (int off = 32; off; off >>= 1) s += __shfl_xor(s, off);

  float qs = 0.f;
  for (int j = 0; j < 32; ++j) {
    int c = l + 64 * j;
    if (c < MEM) {
      float p = row_lds[c] / s;
      float d = p - LAMBDA;
      float q = fmaxf(d, 0.f) * p / (fabsf(d) + EPS);
      row_lds[c] = q;
      qs += q;
    }
  }
#pragma unroll
  for (int off = 32; off; off >>= 1) qs += __shfl_xor(qs, off);
  const float denom = fmaxf(qs, EPS);

  float4 oa0 = {0.f, 0.f, 0.f, 0.f};
  float4 oa1 = {0.f, 0.f, 0.f, 0.f};
  for (int j = 0; j < 32; ++j) {
    int c = l + 64 * j;
    float a = 0.f;
    if (c < MEM) {
      a = row_lds[c] / denom;
      att[(size_t)grow * MEM + c] = a;
    }
    unsigned long long msk = __ballot(a > 0.f);
    while (msk) {
      int b = __ffsll(msk) - 1;
      msk &= msk - 1;
      float av = __shfl(a, b);
      int cc = b + 64 * j;
      const float* wp = Wt + (size_t)cc * FEA;
      float4 w0 = *(const float4*)(wp + 4 * l);
      float4 w1 = *(const float4*)(wp + 256 + 4 * l);
      oa0.x = fmaf(av, w0.x, oa0.x); oa0.y = fmaf(av, w0.y, oa0.y);
      oa0.z = fmaf(av, w0.z, oa0.z); oa0.w = fmaf(av, w0.w, oa0.w);
      oa1.x = fmaf(av, w1.x, oa1.x); oa1.y = fmaf(av, w1.y, oa1.y);
      oa1.z = fmaf(av, w1.z, oa1.z); oa1.w = fmaf(av, w1.w, oa1.w);
    }
  }
  float* op = out + (size_t)grow * FEA;
  *(float4*)(op + 4 * l) = oa0;
  *(float4*)(op + 256 + 4 * l) = oa1;
}

// ------------------------------------------------------------------
extern "C" void kernel_launch(void* const* d_in, const int* in_sizes, int n_in,
                              void* d_out, int out_size, void* d_ws, size_t ws_size,
                              hipStream_t stream) {
  (void)in_sizes; (void)n_in; (void)out_size;
  const float* x = (const float*)d_in[0];
  const float* W = (const float*)d_in[1];
  float* out = (float*)d_out;
  float* att = (float*)d_out + (size_t)NROWS * FEA;

  const size_t w_need = (size_t)PLW * 2 * sizeof(ushort_t);  // 4 MB
  if (ws_size >= w_need) {
    ushort_t* xpl = (ushort_t*)d_out;  // out region: exactly fits 2 x-planes
    ushort_t* wpl = (ushort_t*)d_ws;
    split_all<<<3072, 256, 0, stream>>>(x, W, xpl, wpl);
    gemm_mfma12<<<8192, 512, 0, stream>>>(xpl, wpl, att);
  } else {
    dim3 g1(NROWS / 128, (MEM + 127) / 128);
    gemm_scores<<<g1, 256, 0, stream>>>(x, W, att);
  }
  softmax_shrink_out<<<NROWS / 8, 512, 0, stream>>>(W, out, att);
}